// Round 9
// baseline (296.506 us; speedup 1.0000x reference)
//
#include <hip/hip_runtime.h>
#include <math.h>

#define NT 256

typedef short bf16x8 __attribute__((ext_vector_type(8)));
typedef float f32x4 __attribute__((ext_vector_type(4)));

__device__ __forceinline__ float silu_f(float z) {
    return z / (1.0f + __expf(-z));
}
__device__ __forceinline__ unsigned short f2bf(float f) {
    unsigned int u = __float_as_uint(f);
    u += 0x7FFFu + ((u >> 16) & 1u);          // round-to-nearest-even
    return (unsigned short)(u >> 16);
}
__device__ __forceinline__ float bf2f(unsigned short s) {
    return __uint_as_float(((unsigned int)s) << 16);
}

__global__ __launch_bounds__(NT, 3) void backflow_kernel(
    const float* __restrict__ x,
    const float* __restrict__ phi_w1, const float* __restrict__ phi_b1,
    const float* __restrict__ phi_w2, const float* __restrict__ phi_b2,
    const float* __restrict__ psi_w1, const float* __restrict__ psi_b1,
    const float* __restrict__ psi_w2, const float* __restrict__ psi_b2,
    const float* __restrict__ psi_w3, const float* __restrict__ psi_b3,
    const float* __restrict__ bf_scale,
    float* __restrict__ out)
{
    // A = H (64 j x 128 k) as bf16 hi/lo, XOR-swizzled rows
    __shared__ __align__(16) unsigned short A_hi[64 * 128];
    __shared__ __align__(16) unsigned short A_lo[64 * 128];
    __shared__ __align__(16) float x_l4[64 * 4];
    __shared__ __align__(16) float upd_l[8 * 132];
    __shared__ __align__(16) float u1_l[8 * 132];
    __shared__ float red_l[48];

    const int tid  = threadIdx.x;
    const int b    = blockIdx.x >> 3;
    const int i0   = (blockIdx.x & 7) * 8;
    const int wv   = tid >> 6;          // wave 0..3
    const int lane = tid & 63;
    const int lr   = lane & 15;
    const int lg   = lane >> 4;

    // ---- W2 fragments (hi/lo bf16), register resident. wave wv owns c-tiles {wv, wv+4} ----
    bf16x8 bh[2][4], bl[2][4];
    float b2c[2];
    #pragma unroll
    for (int c2 = 0; c2 < 2; ++c2) {
        const int ct = wv + 4 * c2;
        const int n  = ct * 16 + lr;
        b2c[c2] = phi_b2[n];
        #pragma unroll
        for (int ks = 0; ks < 4; ++ks) {
            #pragma unroll
            for (int e = 0; e < 8; ++e) {
                const int k = ks * 32 + lg * 8 + e;
                const float w = phi_w2[k * 128 + n];
                const unsigned short h = f2bf(w);
                bh[c2][ks][e] = (short)h;
                bl[c2][ks][e] = (short)f2bf(w - bf2f(h));
            }
        }
    }

    // ---- W1 columns for this thread's k-quad ----
    const int kq = (tid & 31) * 4;      // channels kq..kq+3
    const int jg = tid >> 5;            // j-group 0..7 -> j = jg*8 .. jg*8+7
    float w1r[44];
    #pragma unroll
    for (int d = 0; d < 11; ++d)
        #pragma unroll
        for (int kk = 0; kk < 4; ++kk)
            w1r[d * 4 + kk] = phi_w1[d * 128 + kq + kk];
    float b1r[4];
    #pragma unroll
    for (int kk = 0; kk < 4; ++kk) b1r[kk] = phi_b1[kq + kk];

    // ---- stage x ----
    if (tid < 64) {
        x_l4[tid * 4 + 0] = x[b * 192 + tid * 3 + 0];
        x_l4[tid * 4 + 1] = x[b * 192 + tid * 3 + 1];
        x_l4[tid * 4 + 2] = x[b * 192 + tid * 3 + 2];
        x_l4[tid * 4 + 3] = 0.0f;
    }
    __syncthreads();

    #pragma unroll 1
    for (int il = 0; il < 8; ++il) {
        const int i = i0 + il;
        const float xi0 = x_l4[i * 4 + 0], xi1 = x_l4[i * 4 + 1], xi2 = x_l4[i * 4 + 2];
        float preb[4];
        #pragma unroll
        for (int kk = 0; kk < 4; ++kk)
            preb[kk] = b1r[kk] + xi0 * w1r[0 + kk] + xi1 * w1r[4 + kk] + xi2 * w1r[8 + kk];

        // ---- layer-1: H[j][kq..kq+3] fp32 -> bf16 hi/lo into LDS ----
        #pragma unroll
        for (int jj = 0; jj < 8; ++jj) {
            const int j = jg * 8 + jj;
            const float4 xj4 = *(const float4*)&x_l4[j * 4];
            const float r0 = xi0 - xj4.x, r1 = xi1 - xj4.y, r2 = xi2 - xj4.z;
            const float r2s = r0 * r0 + r1 * r1 + r2 * r2;
            const float rn  = sqrtf(r2s + 1e-12f);
            unsigned short hh[4], ll[4];
            #pragma unroll
            for (int kk = 0; kk < 4; ++kk) {
                const float p = preb[kk]
                    + xj4.x * w1r[12 + kk] + xj4.y * w1r[16 + kk] + xj4.z * w1r[20 + kk]
                    + r0 * w1r[24 + kk] + r1 * w1r[28 + kk] + r2 * w1r[32 + kk]
                    + rn * w1r[36 + kk] + r2s * w1r[40 + kk];
                const float h = silu_f(p);
                hh[kk] = f2bf(h);
                ll[kk] = f2bf(h - bf2f(hh[kk]));
            }
            const int byte = ((j * 128 + kq) * 2) ^ ((j & 7) << 4);
            *(ushort4*)((char*)A_hi + byte) = make_ushort4(hh[0], hh[1], hh[2], hh[3]);
            *(ushort4*)((char*)A_lo + byte) = make_ushort4(ll[0], ll[1], ll[2], ll[3]);
        }
        __syncthreads();

        // ---- layer-2 GEMM (MFMA, 3-term bf16 split) + silu + masked j-sum ----
        if (tid < 3) upd_l[il * 132 + tid] = x_l4[i * 4 + tid];
        float msum0 = 0.0f, msum1 = 0.0f;
        const int a_base = lr * 256 + lg * 16;
        const int a_swz  = (lr & 7) << 4;
        #pragma unroll
        for (int jt = 0; jt < 4; ++jt) {
            bf16x8 ah[4], al[4];
            #pragma unroll
            for (int ks = 0; ks < 4; ++ks) {
                const int off = (jt * 4096 + ks * 64 + a_base) ^ a_swz;
                ah[ks] = *(const bf16x8*)((const char*)A_hi + off);
                al[ks] = *(const bf16x8*)((const char*)A_lo + off);
            }
            #pragma unroll
            for (int c2 = 0; c2 < 2; ++c2) {
                f32x4 acc = {0.0f, 0.0f, 0.0f, 0.0f};
                #pragma unroll
                for (int ks = 0; ks < 4; ++ks) {
                    acc = __builtin_amdgcn_mfma_f32_16x16x32_bf16(ah[ks], bh[c2][ks], acc, 0, 0, 0);
                    acc = __builtin_amdgcn_mfma_f32_16x16x32_bf16(al[ks], bh[c2][ks], acc, 0, 0, 0);
                    acc = __builtin_amdgcn_mfma_f32_16x16x32_bf16(ah[ks], bl[c2][ks], acc, 0, 0, 0);
                }
                #pragma unroll
                for (int v = 0; v < 4; ++v) {
                    const int row = jt * 16 + lg * 4 + v;   // j index
                    const float mv = silu_f(acc[v] + b2c[c2]);
                    const float add = (row == i) ? 0.0f : mv;
                    if (c2 == 0) msum0 += add; else msum1 += add;
                }
            }
        }
        msum0 += __shfl_xor(msum0, 16, 64); msum0 += __shfl_xor(msum0, 32, 64);
        msum1 += __shfl_xor(msum1, 16, 64); msum1 += __shfl_xor(msum1, 32, 64);
        if (lane < 16) {
            upd_l[il * 132 + 3 + (wv) * 16 + lr]     = msum0;
            upd_l[il * 132 + 3 + (wv + 4) * 16 + lr] = msum1;
        }
        __syncthreads();
    }

    // ---- psi MLP: rep (tid>>7) handles 4 nodes; c = tid&127 ----
    const int c   = tid & 127;
    const int rep = tid >> 7;
    const int n0  = rep * 4;
    float a4[4];
    const float pb1 = psi_b1[c];
    #pragma unroll
    for (int nn = 0; nn < 4; ++nn) a4[nn] = pb1;
    for (int k = 0; k < 131; ++k) {
        const float w = psi_w1[k * 128 + c];
        #pragma unroll
        for (int nn = 0; nn < 4; ++nn) a4[nn] += upd_l[(n0 + nn) * 132 + k] * w;
    }
    #pragma unroll
    for (int nn = 0; nn < 4; ++nn) u1_l[(n0 + nn) * 132 + c] = silu_f(a4[nn]);
    __syncthreads();

    const float pb2 = psi_b2[c];
    #pragma unroll
    for (int nn = 0; nn < 4; ++nn) a4[nn] = pb2;
    for (int k = 0; k < 128; ++k) {
        const float w = psi_w2[k * 128 + c];
        #pragma unroll
        for (int nn = 0; nn < 4; ++nn) a4[nn] += u1_l[(n0 + nn) * 132 + k] * w;
    }
    float u2[4];
    #pragma unroll
    for (int nn = 0; nn < 4; ++nn) u2[nn] = silu_f(a4[nn]);

    const float w30 = psi_w3[c * 3 + 0];
    const float w31 = psi_w3[c * 3 + 1];
    const float w32 = psi_w3[c * 3 + 2];
    float pd[4][3];
    #pragma unroll
    for (int nn = 0; nn < 4; ++nn) {
        pd[nn][0] = u2[nn] * w30;
        pd[nn][1] = u2[nn] * w31;
        pd[nn][2] = u2[nn] * w32;
    }
    #pragma unroll
    for (int off = 32; off > 0; off >>= 1) {
        #pragma unroll
        for (int nn = 0; nn < 4; ++nn) {
            pd[nn][0] += __shfl_xor(pd[nn][0], off, 64);
            pd[nn][1] += __shfl_xor(pd[nn][1], off, 64);
            pd[nn][2] += __shfl_xor(pd[nn][2], off, 64);
        }
    }
    if (lane == 0) {
        #pragma unroll
        for (int nn = 0; nn < 4; ++nn) {
            red_l[wv * 12 + nn * 3 + 0] = pd[nn][0];
            red_l[wv * 12 + nn * 3 + 1] = pd[nn][1];
            red_l[wv * 12 + nn * 3 + 2] = pd[nn][2];
        }
    }
    __syncthreads();
    if (tid < 24) {
        const int n = tid / 3, d = tid % 3;
        const int wa = (n < 4) ? 0 : 2;
        const float dx = red_l[wa * 12 + (n & 3) * 3 + d]
                       + red_l[(wa + 1) * 12 + (n & 3) * 3 + d] + psi_b3[d];
        out[(b * 64 + i0 + n) * 3 + d] = tanhf(dx) * fmaxf(bf_scale[0], 0.0f);
    }
}

extern "C" void kernel_launch(void* const* d_in, const int* in_sizes, int n_in,
                              void* d_out, int out_size, void* d_ws, size_t ws_size,
                              hipStream_t stream) {
    const float* x        = (const float*)d_in[0];
    // d_in[1] = spin (unused: mask is all-ones off-diagonal)
    const float* phi_w1   = (const float*)d_in[2];
    const float* phi_b1   = (const float*)d_in[3];
    const float* phi_w2   = (const float*)d_in[4];
    const float* phi_b2   = (const float*)d_in[5];
    const float* psi_w1   = (const float*)d_in[6];
    const float* psi_b1   = (const float*)d_in[7];
    const float* psi_w2   = (const float*)d_in[8];
    const float* psi_b2   = (const float*)d_in[9];
    const float* psi_w3   = (const float*)d_in[10];
    const float* psi_b3   = (const float*)d_in[11];
    const float* bf_scale = (const float*)d_in[12];
    float* out = (float*)d_out;

    backflow_kernel<<<dim3(2048), dim3(NT), 0, stream>>>(
        x, phi_w1, phi_b1, phi_w2, phi_b2,
        psi_w1, psi_b1, psi_w2, psi_b2, psi_w3, psi_b3,
        bf_scale, out);
}

// Round 11
// 258.604 us; speedup vs baseline: 1.1466x; 1.1466x over previous
//
#include <hip/hip_runtime.h>
#include <math.h>

#define NT 256

typedef short bf16x8 __attribute__((ext_vector_type(8)));
typedef float f32x4 __attribute__((ext_vector_type(4)));

// IEEE-div silu — R3/R9-proven. Do NOT replace with rcp/NR (fails replay check).
__device__ __forceinline__ float silu_f(float z) {
    return z / (1.0f + __expf(-z));
}
__device__ __forceinline__ unsigned short f2bf(float f) {
    unsigned int u = __float_as_uint(f);
    u += 0x7FFFu + ((u >> 16) & 1u);          // round-to-nearest-even
    return (unsigned short)(u >> 16);
}
__device__ __forceinline__ float bf2f(unsigned short s) {
    return __uint_as_float(((unsigned int)s) << 16);
}

__global__ __launch_bounds__(NT, 2) void backflow_kernel(
    const float* __restrict__ x,
    const float* __restrict__ phi_w1, const float* __restrict__ phi_b1,
    const float* __restrict__ phi_w2, const float* __restrict__ phi_b2,
    const float* __restrict__ psi_w1, const float* __restrict__ psi_b1,
    const float* __restrict__ psi_w2, const float* __restrict__ psi_b2,
    const float* __restrict__ psi_w3, const float* __restrict__ psi_b3,
    const float* __restrict__ bf_scale,
    float* __restrict__ out)
{
    // A = H (64 j x 128 k) as bf16 hi/lo, XOR-swizzled rows.
    // A_hi is dead after the il-loop; its space is reused for u1_l in the psi phase.
    __shared__ __align__(16) unsigned short A_hi[64 * 128];
    __shared__ __align__(16) unsigned short A_lo[64 * 128];
    __shared__ __align__(16) float x_l4[64 * 4];
    __shared__ __align__(16) float rf[64 * 8];   // per-j: xj0,xj1,xj2,r0 | r1,r2,|r|,|r|^2
    __shared__ __align__(16) float upd_l[8 * 132];
    __shared__ float red_l[48];

    const int tid  = threadIdx.x;
    const int b    = blockIdx.x >> 3;
    const int i0   = (blockIdx.x & 7) * 8;
    const int wv   = tid >> 6;          // wave 0..3
    const int lane = tid & 63;
    const int lr   = lane & 15;
    const int lg   = lane >> 4;

    // ---- W2 fragments (hi/lo bf16), register resident. wave wv owns c-tiles {wv, wv+4} ----
    bf16x8 bh[2][4], bl[2][4];
    float b2c[2];
    #pragma unroll
    for (int c2 = 0; c2 < 2; ++c2) {
        const int ct = wv + 4 * c2;
        const int n  = ct * 16 + lr;
        b2c[c2] = phi_b2[n];
        #pragma unroll
        for (int ks = 0; ks < 4; ++ks) {
            #pragma unroll
            for (int e = 0; e < 8; ++e) {
                const int k = ks * 32 + lg * 8 + e;
                const float w = phi_w2[k * 128 + n];
                const unsigned short h = f2bf(w);
                bh[c2][ks][e] = (short)h;
                bl[c2][ks][e] = (short)f2bf(w - bf2f(h));
            }
        }
    }

    // ---- W1 columns for this thread's k-quad ----
    const int kq = (tid & 31) * 4;      // channels kq..kq+3
    const int jg = tid >> 5;            // j-group 0..7 -> j = jg*8 .. jg*8+7
    float w1r[44];
    #pragma unroll
    for (int d = 0; d < 11; ++d)
        #pragma unroll
        for (int kk = 0; kk < 4; ++kk)
            w1r[d * 4 + kk] = phi_w1[d * 128 + kq + kk];
    float b1r[4];
    #pragma unroll
    for (int kk = 0; kk < 4; ++kk) b1r[kk] = phi_b1[kq + kk];

    // ---- stage x ----
    if (tid < 64) {
        x_l4[tid * 4 + 0] = x[b * 192 + tid * 3 + 0];
        x_l4[tid * 4 + 1] = x[b * 192 + tid * 3 + 1];
        x_l4[tid * 4 + 2] = x[b * 192 + tid * 3 + 2];
        x_l4[tid * 4 + 3] = 0.0f;
    }
    __syncthreads();

    #pragma unroll 1
    for (int il = 0; il < 8; ++il) {
        const int i = i0 + il;
        const float xi0 = x_l4[i * 4 + 0], xi1 = x_l4[i * 4 + 1], xi2 = x_l4[i * 4 + 2];

        // ---- geometry for this i, computed ONCE by lane j (was 32x redundant in R3) ----
        if (tid < 64) {
            const int j = tid;
            const float4 xj4 = *(const float4*)&x_l4[j * 4];
            const float r0 = xi0 - xj4.x, r1 = xi1 - xj4.y, r2 = xi2 - xj4.z;
            const float r2s = r0 * r0 + r1 * r1 + r2 * r2;
            const float rn  = sqrtf(r2s + 1e-12f);
            float4* p = (float4*)&rf[j * 8];
            p[0] = make_float4(xj4.x, xj4.y, xj4.z, r0);
            p[1] = make_float4(r1, r2, rn, r2s);
        }
        __syncthreads();   // barF: rf ready; also fences prev-il layer-2 A reads

        if (tid < 3) upd_l[il * 132 + tid] = x_l4[i * 4 + tid];

        float preb[4];
        #pragma unroll
        for (int kk = 0; kk < 4; ++kk)
            preb[kk] = b1r[kk] + xi0 * w1r[0 + kk] + xi1 * w1r[4 + kk] + xi2 * w1r[8 + kk];

        // ---- layer-1: H[j][kq..kq+3] fp32 -> bf16 hi/lo into LDS ----
        #pragma unroll
        for (int jj = 0; jj < 8; ++jj) {
            const int j = jg * 8 + jj;
            const float4 f0 = *(const float4*)&rf[j * 8];
            const float4 f1 = *(const float4*)&rf[j * 8 + 4];
            unsigned short hh[4], ll[4];
            #pragma unroll
            for (int kk = 0; kk < 4; ++kk) {
                const float p = preb[kk]
                    + f0.x * w1r[12 + kk] + f0.y * w1r[16 + kk] + f0.z * w1r[20 + kk]
                    + f0.w * w1r[24 + kk] + f1.x * w1r[28 + kk] + f1.y * w1r[32 + kk]
                    + f1.z * w1r[36 + kk] + f1.w * w1r[40 + kk];
                const float h = silu_f(p);
                hh[kk] = f2bf(h);
                ll[kk] = f2bf(h - bf2f(hh[kk]));
            }
            const int byte = ((j * 128 + kq) * 2) ^ ((j & 7) << 4);
            *(ushort4*)((char*)A_hi + byte) = make_ushort4(hh[0], hh[1], hh[2], hh[3]);
            *(ushort4*)((char*)A_lo + byte) = make_ushort4(ll[0], ll[1], ll[2], ll[3]);
        }
        __syncthreads();   // barA: A ready

        // ---- layer-2 GEMM (MFMA, 3-term bf16 split) + silu + masked j-sum ----
        float msum0 = 0.0f, msum1 = 0.0f;
        const int a_base = lr * 256 + lg * 16;
        const int a_swz  = (lr & 7) << 4;
        #pragma unroll
        for (int jt = 0; jt < 4; ++jt) {
            bf16x8 ah[4], al[4];
            #pragma unroll
            for (int ks = 0; ks < 4; ++ks) {
                const int off = (jt * 4096 + ks * 64 + a_base) ^ a_swz;
                ah[ks] = *(const bf16x8*)((const char*)A_hi + off);
                al[ks] = *(const bf16x8*)((const char*)A_lo + off);
            }
            #pragma unroll
            for (int c2 = 0; c2 < 2; ++c2) {
                f32x4 acc = {0.0f, 0.0f, 0.0f, 0.0f};
                #pragma unroll
                for (int ks = 0; ks < 4; ++ks) {
                    acc = __builtin_amdgcn_mfma_f32_16x16x32_bf16(ah[ks], bh[c2][ks], acc, 0, 0, 0);
                    acc = __builtin_amdgcn_mfma_f32_16x16x32_bf16(al[ks], bh[c2][ks], acc, 0, 0, 0);
                    acc = __builtin_amdgcn_mfma_f32_16x16x32_bf16(ah[ks], bl[c2][ks], acc, 0, 0, 0);
                }
                #pragma unroll
                for (int v = 0; v < 4; ++v) {
                    const int row = jt * 16 + lg * 4 + v;   // j index
                    const float mv = silu_f(acc[v] + b2c[c2]);
                    const float add = (row == i) ? 0.0f : mv;
                    if (c2 == 0) msum0 += add; else msum1 += add;
                }
            }
        }
        msum0 += __shfl_xor(msum0, 16, 64); msum0 += __shfl_xor(msum0, 32, 64);
        msum1 += __shfl_xor(msum1, 16, 64); msum1 += __shfl_xor(msum1, 32, 64);
        if (lane < 16) {
            upd_l[il * 132 + 3 + (wv) * 16 + lr]     = msum0;
            upd_l[il * 132 + 3 + (wv + 4) * 16 + lr] = msum1;
        }
    }
    __syncthreads();       // A dead from here; reuse its space for u1_l

    float* u1_l = (float*)A_hi;   // 8*132*4 = 4224 B < 16 KB alias

    // ---- psi MLP: rep (tid>>7) handles 4 nodes; c = tid&127 ----
    const int c   = tid & 127;
    const int rep = tid >> 7;
    const int n0  = rep * 4;
    float a4[4];
    const float pb1 = psi_b1[c];
    #pragma unroll
    for (int nn = 0; nn < 4; ++nn) a4[nn] = pb1;
    #pragma unroll 4
    for (int k = 0; k < 131; ++k) {
        const float w = psi_w1[k * 128 + c];
        #pragma unroll
        for (int nn = 0; nn < 4; ++nn) a4[nn] += upd_l[(n0 + nn) * 132 + k] * w;
    }
    #pragma unroll
    for (int nn = 0; nn < 4; ++nn) u1_l[(n0 + nn) * 132 + c] = silu_f(a4[nn]);
    __syncthreads();

    const float pb2 = psi_b2[c];
    #pragma unroll
    for (int nn = 0; nn < 4; ++nn) a4[nn] = pb2;
    #pragma unroll 4
    for (int k = 0; k < 128; ++k) {
        const float w = psi_w2[k * 128 + c];
        #pragma unroll
        for (int nn = 0; nn < 4; ++nn) a4[nn] += u1_l[(n0 + nn) * 132 + k] * w;
    }
    float u2[4];
    #pragma unroll
    for (int nn = 0; nn < 4; ++nn) u2[nn] = silu_f(a4[nn]);

    const float w30 = psi_w3[c * 3 + 0];
    const float w31 = psi_w3[c * 3 + 1];
    const float w32 = psi_w3[c * 3 + 2];
    float pd[4][3];
    #pragma unroll
    for (int nn = 0; nn < 4; ++nn) {
        pd[nn][0] = u2[nn] * w30;
        pd[nn][1] = u2[nn] * w31;
        pd[nn][2] = u2[nn] * w32;
    }
    #pragma unroll
    for (int off = 32; off > 0; off >>= 1) {
        #pragma unroll
        for (int nn = 0; nn < 4; ++nn) {
            pd[nn][0] += __shfl_xor(pd[nn][0], off, 64);
            pd[nn][1] += __shfl_xor(pd[nn][1], off, 64);
            pd[nn][2] += __shfl_xor(pd[nn][2], off, 64);
        }
    }
    if (lane == 0) {
        #pragma unroll
        for (int nn = 0; nn < 4; ++nn) {
            red_l[wv * 12 + nn * 3 + 0] = pd[nn][0];
            red_l[wv * 12 + nn * 3 + 1] = pd[nn][1];
            red_l[wv * 12 + nn * 3 + 2] = pd[nn][2];
        }
    }
    __syncthreads();
    if (tid < 24) {
        const int n = tid / 3, d = tid % 3;
        const int wa = (n < 4) ? 0 : 2;
        const float dx = red_l[wa * 12 + (n & 3) * 3 + d]
                       + red_l[(wa + 1) * 12 + (n & 3) * 3 + d] + psi_b3[d];
        out[(b * 64 + i0 + n) * 3 + d] = tanhf(dx) * fmaxf(bf_scale[0], 0.0f);
    }
}

extern "C" void kernel_launch(void* const* d_in, const int* in_sizes, int n_in,
                              void* d_out, int out_size, void* d_ws, size_t ws_size,
                              hipStream_t stream) {
    const float* x        = (const float*)d_in[0];
    // d_in[1] = spin (unused: mask is all-ones off-diagonal)
    const float* phi_w1   = (const float*)d_in[2];
    const float* phi_b1   = (const float*)d_in[3];
    const float* phi_w2   = (const float*)d_in[4];
    const float* phi_b2   = (const float*)d_in[5];
    const float* psi_w1   = (const float*)d_in[6];
    const float* psi_b1   = (const float*)d_in[7];
    const float* psi_w2   = (const float*)d_in[8];
    const float* psi_b2   = (const float*)d_in[9];
    const float* psi_w3   = (const float*)d_in[10];
    const float* psi_b3   = (const float*)d_in[11];
    const float* bf_scale = (const float*)d_in[12];
    float* out = (float*)d_out;

    backflow_kernel<<<dim3(2048), dim3(NT), 0, stream>>>(
        x, phi_w1, phi_b1, phi_w2, phi_b2,
        psi_w1, psi_b1, psi_w2, psi_b2, psi_w3, psi_b3,
        bf_scale, out);
}